// Round 11
// baseline (4515.730 us; speedup 1.0000x reference)
//
#include <hip/hip_runtime.h>
#include <math.h>

// Problem constants
#define B_    256
#define NPTS  1024
#define T_    50

// ---------------------------------------------------------------------------
// ws layout (bytes):
//   [0,       786432)   wq   f32 packed W_hh for the (cc,kq) thread layout:
//                       wq[((kk*6+j)*128+cc)*4+c4] = whh[R*256 + kk*4+c4],
//                       R = (j>>1)*256 + (j&1)*128 + cc,  kk in [0,64)
//   [786432,  1310720)  henc u32 [256][512]  (f32-bit maxpool via atomicMax)
// ---------------------------------------------------------------------------

__global__ __launch_bounds__(256) void prep_kernel(const float* __restrict__ whh,
                                                   float* __restrict__ wq,
                                                   unsigned* __restrict__ henc) {
  int idx = blockIdx.x * 256 + threadIdx.x;   // grid 768*256 = 196608
  if (idx < 196608) {
    int c4 = idx & 3;
    int r = idx >> 2;            // ((kk*6)+j)*128 + cc
    int cc = r & 127;
    int q = r >> 7;              // kk*6 + j
    int j = q % 6;
    int kk = q / 6;              // k4 index 0..63
    int R = (j >> 1) * 256 + (j & 1) * 128 + cc;
    wq[idx] = whh[R * 256 + kk * 4 + c4];
  }
  if (idx < 131072) henc[idx] = 0u;           // bits 0 == +0.0f; relu>=0 valid
}

// ---------------------------------------------------------------------------
// Encoder (unchanged from passing round 10 — bit-identical henc): w2 staged
// to LDS once, register-tiled 8x8 GEMM, LDS-atomic maxpool.
// ---------------------------------------------------------------------------
__global__ __launch_bounds__(512, 4) void enc_kernel(
    const float* __restrict__ data,
    const float* __restrict__ w1, const float* __restrict__ b1,
    const float* __restrict__ w2, const float* __restrict__ b2,
    const float* __restrict__ w3, const float* __restrict__ b3,
    unsigned* __restrict__ henc) {
  __shared__ float w2_l[8192];
  __shared__ float h2t[128][72];
  __shared__ unsigned pool_l[512];
  const int t = threadIdx.x;
  const int b = blockIdx.x >> 1;
  const int half = blockIdx.x & 1;
  const int og = t & 63;
  const int pg = t >> 6;
  const int spt = t & 63;
  const int scg = t >> 6;

  for (int i = t; i < 8192; i += 512) w2_l[i] = w2[i];
  pool_l[t] = 0u;
  __syncthreads();

  float m[8];
#pragma unroll
  for (int oo = 0; oo < 8; ++oo) m[oo] = 0.0f;
  const float4 b3a = *(const float4*)(b3 + og * 8);
  const float4 b3b = *(const float4*)(b3 + og * 8 + 4);
  const float* __restrict__ w3l = w3 + og * 8;

#pragma unroll 1
  for (int tile = 0; tile < 8; ++tile) {
    {
      const int ptg = b * NPTS + half * 512 + tile * 64 + spt;
      const float x0 = data[ptg * 3], x1 = data[ptg * 3 + 1], x2 = data[ptg * 3 + 2];
      float a[16];
#pragma unroll
      for (int c = 0; c < 16; ++c) a[c] = b2[scg * 16 + c];
#pragma unroll 4
      for (int j = 0; j < 64; ++j) {
        float hj = fmaf(x0, w1[j], fmaf(x1, w1[64 + j], fmaf(x2, w1[128 + j], b1[j])));
        hj = fmaxf(hj, 0.0f);
        const float* __restrict__ w2r = w2_l + j * 128 + scg * 16;
#pragma unroll
        for (int c = 0; c < 16; ++c) a[c] = fmaf(hj, w2r[c], a[c]);
      }
#pragma unroll
      for (int c = 0; c < 16; ++c) h2t[scg * 16 + c][spt] = fmaxf(a[c], 0.0f);
    }
    __syncthreads();

    float acc[64];
#pragma unroll
    for (int pp2 = 0; pp2 < 8; ++pp2) {
      acc[pp2 * 8 + 0] = b3a.x; acc[pp2 * 8 + 1] = b3a.y;
      acc[pp2 * 8 + 2] = b3a.z; acc[pp2 * 8 + 3] = b3a.w;
      acc[pp2 * 8 + 4] = b3b.x; acc[pp2 * 8 + 5] = b3b.y;
      acc[pp2 * 8 + 6] = b3b.z; acc[pp2 * 8 + 7] = b3b.w;
    }
#pragma unroll 2
    for (int k = 0; k < 128; ++k) {
      const float4 wa = *(const float4*)(w3l + k * 512);
      const float4 wb = *(const float4*)(w3l + k * 512 + 4);
      const float4 pa = *(const float4*)(&h2t[k][pg * 8]);
      const float4 pb = *(const float4*)(&h2t[k][pg * 8 + 4]);
      const float wv8[8] = {wa.x, wa.y, wa.z, wa.w, wb.x, wb.y, wb.z, wb.w};
      const float pv8[8] = {pa.x, pa.y, pa.z, pa.w, pb.x, pb.y, pb.z, pb.w};
#pragma unroll
      for (int pp2 = 0; pp2 < 8; ++pp2)
#pragma unroll
        for (int oo = 0; oo < 8; ++oo)
          acc[pp2 * 8 + oo] = fmaf(pv8[pp2], wv8[oo], acc[pp2 * 8 + oo]);
    }
#pragma unroll
    for (int pp2 = 0; pp2 < 8; ++pp2)
#pragma unroll
      for (int oo = 0; oo < 8; ++oo)
        m[oo] = fmaxf(m[oo], acc[pp2 * 8 + oo]);
    __syncthreads();
  }

#pragma unroll
  for (int oo = 0; oo < 8; ++oo)
    atomicMax(&pool_l[og * 8 + oo], __float_as_uint(m[oo]));
  __syncthreads();
  atomicMax(henc + b * 512 + t, pool_l[t]);
}

// ---------------------------------------------------------------------------
// Fast f64 exp (Cody-Waite + degree-13 Taylor, branch-free, ~1 ulp).
// ---------------------------------------------------------------------------
__device__ __forceinline__ double fexp(double x) {
  const double n = rint(x * 1.44269504088896338700e+00);
  const double r = fma(-n, 1.90821492927058770002e-10,
                       fma(-n, 6.93147180369123816490e-01, x));
  double p = 1.0 / 6227020800.0;                 // 1/13!
  p = fma(p, r, 1.0 / 479001600.0);
  p = fma(p, r, 1.0 / 39916800.0);
  p = fma(p, r, 1.0 / 3628800.0);
  p = fma(p, r, 1.0 / 362880.0);
  p = fma(p, r, 1.0 / 40320.0);
  p = fma(p, r, 1.0 / 5040.0);
  p = fma(p, r, 1.0 / 720.0);
  p = fma(p, r, 1.0 / 120.0);
  p = fma(p, r, 1.0 / 24.0);
  p = fma(p, r, 1.0 / 6.0);
  p = fma(p, r, 0.5);
  p = fma(p, r, 1.0);
  p = fma(p, r, 1.0);
  return ldexp(p, (int)n);
}
__device__ __forceinline__ double fsigm(double x) { return 1.0 / (1.0 + fexp(-x)); }
__device__ __forceinline__ double ftanh(double y) {
  const double e = fexp(-2.0 * y);
  return (1.0 - e) / (1.0 + e);
}

// ---------------------------------------------------------------------------
// GRU rollout, f64, grid 128, block = 2 samples x 640 threads (10 waves),
// __launch_bounds__(640,3) -> 170 VGPR. Matvec thread (cc = t&127,
// kq = t>>7 < 4) owns 6 rows (r/z/n gates x channels {cc, cc+128}) over
// k-quarter [64kq, 64kq+64):
//   - k4i 0..3 HELD in 96 register floats (192 KB/block, loaded once: the
//     rounds-7..10 wall was re-streaming all 768 KB of W_hh every step
//     through one CU's VMEM port ~5 us/step);
//   - k4i 4..15 streamed (576 KB/step, coalesced float4).
// Partials pp[kq][gate][g][ch] summed in the gates phase ((p0+p1)+(p2+p3),
// f64-invisible reassoc). Gates fused on t<512 (thread (c,g) owns h in a
// register); out_mlp = round-10's single-wave-per-sample code on waves 8-9.
// Two barriers per step.
// ---------------------------------------------------------------------------
__global__ __launch_bounds__(640, 3) void gru_kernel(
    const float* __restrict__ henc,     // [256][512] (maxpool bits)
    const float* __restrict__ mw1, const float* __restrict__ mb1,
    const float* __restrict__ mw2, const float* __restrict__ mb2,
    const float* __restrict__ mw3, const float* __restrict__ mb3,
    const float* __restrict__ wih, const float* __restrict__ wq,
    const float* __restrict__ bih, const float* __restrict__ bhh,
    const float* __restrict__ ow1, const float* __restrict__ ob1,
    const float* __restrict__ ow2, const float* __restrict__ ob2,
    const float* __restrict__ ow3, const float* __restrict__ ob3,
    float* __restrict__ dout) {
  __shared__ __align__(16) double h_l[512];   // [g][c]
  __shared__ double pp_l[6144];               // [kq][gate][g][256ch] (48 KB)
  __shared__ double o1_l[2][64];
  __shared__ double o2_l[2][64];
  __shared__ double giab[2][12];              // step-parity double buffer
  __shared__ float wihT[6][768];              // wihT[a][row] = wih[row*6+a]
  __shared__ double bihd[768];
  __shared__ double bhhd[768];

  const int t = threadIdx.x;
  const int s0 = blockIdx.x << 1;
  double* __restrict__ g1a = pp_l;            // phase-0 aliases (pp unused yet)
  double* __restrict__ g2a = pp_l + 512;

  for (int i = t; i < 4608; i += 640) {
    const int a = i / 768, row = i - a * 768;
    wihT[a][row] = wih[row * 6 + a];
  }
  for (int i = t; i < 768; i += 640) {
    bihd[i] = (double)bih[i];
    bhhd[i] = (double)bhh[i];
  }
  __syncthreads();                            // bhhd/wihT ready

  // ---- phase 0: gru_h init MLP (512->256->128->256), f64 ----
  if (t < 512) {
    const int o = t & 255, g = t >> 8;                    // g wave-uniform
    const float* __restrict__ hrow = henc + ((s0 + g) << 9);
    double a = (double)mb1[o];
#pragma unroll 4
    for (int k = 0; k < 512; ++k)
      a = fma((double)hrow[k], (double)mw1[k * 256 + o], a);
    g1a[(g << 8) + o] = fmax(a, 0.0);
  }
  __syncthreads();
  if (t < 256) {
    const int o = t & 127, g = t >> 7;
    double a = (double)mb2[o];
#pragma unroll 4
    for (int k = 0; k < 256; ++k) a = fma(g1a[(g << 8) + k], (double)mw2[k * 128 + o], a);
    g2a[(g << 7) + o] = fmax(a, 0.0);
  }
  __syncthreads();
  double hreg = 0.0;
  if (t < 512) {
    const int o = t & 255, g = t >> 8;
    double a = (double)mb3[o];
#pragma unroll 4
    for (int k = 0; k < 128; ++k) a = fma(g2a[(g << 7) + k], (double)mw3[k * 256 + o], a);
    hreg = a;                          // gate thread (c=o, g) owns h[g][c]
    h_l[(g << 8) + o] = a;
  }
  if (t < 12) giab[0][t] = 0.0;
  __syncthreads();                     // also: done with g1a/g2a aliases

  // ---- matvec thread constants + held-weight register load ----
  const int cc = t & 127;
  const int kq = (t >> 7) & 3;         // valid for t<512
  float wh[96];                        // held W: [k4i 0..3][j 0..5][4]
  if (t < 512) {
#pragma unroll
    for (int k4i = 0; k4i < 4; ++k4i)
#pragma unroll
      for (int j = 0; j < 6; ++j) {
        const int kk = (kq << 4) + k4i;
        const float4 v = *(const float4*)(wq + (((kk * 6 + j) << 7) + cc) * 4);
        wh[(k4i * 6 + j) * 4 + 0] = v.x; wh[(k4i * 6 + j) * 4 + 1] = v.y;
        wh[(k4i * 6 + j) * 4 + 2] = v.z; wh[(k4i * 6 + j) * 4 + 3] = v.w;
      }
  }

  // matvec body: acc[j][g], j = gate*2 + chHalf; publish to pp_l
#define MV_BODY() {                                                          \
    double acc[6][2];                                                        \
    _Pragma("unroll")                                                        \
    for (int j = 0; j < 6; ++j) {                                            \
      const double s = (kq == 0) ? bhhd[(j >> 1) * 256 + (j & 1) * 128 + cc] : 0.0; \
      acc[j][0] = s; acc[j][1] = s;                                          \
    }                                                                        \
    _Pragma("unroll")                                                        \
    for (int k4i = 4; k4i < 16; ++k4i) {       /* streamed */                \
      const int kk = (kq << 4) + k4i;                                        \
      float4 w6[6];                                                          \
      _Pragma("unroll")                                                      \
      for (int j = 0; j < 6; ++j)                                            \
        w6[j] = *(const float4*)(wq + (((kk * 6 + j) << 7) + cc) * 4);       \
      const double2 hA0 = *(const double2*)(h_l + (kk << 2));                \
      const double2 hB0 = *(const double2*)(h_l + (kk << 2) + 2);            \
      const double2 hA1 = *(const double2*)(h_l + 256 + (kk << 2));          \
      const double2 hB1 = *(const double2*)(h_l + 256 + (kk << 2) + 2);      \
      _Pragma("unroll")                                                      \
      for (int j = 0; j < 6; ++j) {                                          \
        const double w0 = (double)w6[j].x, w1v = (double)w6[j].y;            \
        const double w2v = (double)w6[j].z, w3v = (double)w6[j].w;           \
        acc[j][0] = fma(hA0.x, w0, acc[j][0]); acc[j][0] = fma(hA0.y, w1v, acc[j][0]); \
        acc[j][0] = fma(hB0.x, w2v, acc[j][0]); acc[j][0] = fma(hB0.y, w3v, acc[j][0]); \
        acc[j][1] = fma(hA1.x, w0, acc[j][1]); acc[j][1] = fma(hA1.y, w1v, acc[j][1]); \
        acc[j][1] = fma(hB1.x, w2v, acc[j][1]); acc[j][1] = fma(hB1.y, w3v, acc[j][1]); \
      }                                                                      \
    }                                                                        \
    _Pragma("unroll")                                                        \
    for (int k4i = 0; k4i < 4; ++k4i) {        /* held (registers) */        \
      const int kk = (kq << 4) + k4i;                                        \
      const double2 hA0 = *(const double2*)(h_l + (kk << 2));                \
      const double2 hB0 = *(const double2*)(h_l + (kk << 2) + 2);            \
      const double2 hA1 = *(const double2*)(h_l + 256 + (kk << 2));          \
      const double2 hB1 = *(const double2*)(h_l + 256 + (kk << 2) + 2);      \
      _Pragma("unroll")                                                      \
      for (int j = 0; j < 6; ++j) {                                          \
        const double w0 = (double)wh[(k4i * 6 + j) * 4 + 0];                 \
        const double w1v = (double)wh[(k4i * 6 + j) * 4 + 1];                \
        const double w2v = (double)wh[(k4i * 6 + j) * 4 + 2];                \
        const double w3v = (double)wh[(k4i * 6 + j) * 4 + 3];                \
        acc[j][0] = fma(hA0.x, w0, acc[j][0]); acc[j][0] = fma(hA0.y, w1v, acc[j][0]); \
        acc[j][0] = fma(hB0.x, w2v, acc[j][0]); acc[j][0] = fma(hB0.y, w3v, acc[j][0]); \
        acc[j][1] = fma(hA1.x, w0, acc[j][1]); acc[j][1] = fma(hA1.y, w1v, acc[j][1]); \
        acc[j][1] = fma(hB1.x, w2v, acc[j][1]); acc[j][1] = fma(hB1.y, w3v, acc[j][1]); \
      }                                                                      \
    }                                                                        \
    _Pragma("unroll")                                                        \
    for (int j = 0; j < 6; ++j) {              /* publish partials */        \
      const int ch = (j & 1) * 128 + cc;                                     \
      pp_l[((kq * 3 + (j >> 1)) << 9) + ch] = acc[j][0];                     \
      pp_l[((kq * 3 + (j >> 1)) << 9) + 256 + ch] = acc[j][1];               \
    }                                                                        \
  }

  // ---- prologue: pp = partials of Whh @ h_init ----
  if (t < 512) MV_BODY();
  __syncthreads();

  for (int step = 0; step < T_; ++step) {
    // ---- A: gates + h update (t<512, thread = (c, g)) ----
    if (t < 512) {
      const int c = t & 255, g = t >> 8;
      const int gg = (g << 8) + c;
      const double cr = (pp_l[(0 << 9) + gg] + pp_l[(3 << 9) + gg]) +
                        (pp_l[(6 << 9) + gg] + pp_l[(9 << 9) + gg]);
      const double cz = (pp_l[(1 << 9) + gg] + pp_l[(4 << 9) + gg]) +
                        (pp_l[(7 << 9) + gg] + pp_l[(10 << 9) + gg]);
      const double cn = (pp_l[(2 << 9) + gg] + pp_l[(5 << 9) + gg]) +
                        (pp_l[(8 << 9) + gg] + pp_l[(11 << 9) + gg]);
      double gr = bihd[c], gz = bihd[256 + c], gn = bihd[512 + c];
#pragma unroll
      for (int a = 0; a < 6; ++a) {
        const double xa = giab[step & 1][g * 6 + a];
        gr = fma((double)wihT[a][c], xa, gr);
        gz = fma((double)wihT[a][256 + c], xa, gz);
        gn = fma((double)wihT[a][512 + c], xa, gn);
      }
      const double rv = fsigm(cr + gr);
      const double zv = fsigm(cz + gz);
      const double nv = ftanh(fma(rv, cn, gn));
      hreg = fma(zv, hreg - nv, nv);
      h_l[gg] = hreg;
    }
    __syncthreads();                    // h published

    // ---- B: matvec (t<512) || full out_mlp (waves 8-9) ----
    if (t < 512) {
      MV_BODY();
    } else {
      const int g = (t - 512) >> 6;     // wave 8 -> g=0, wave 9 -> g=1
      const int j = (t - 512) & 63;
      // L1: 256 -> 64
      double a = (double)ob1[j];
#pragma unroll 4
      for (int k = 0; k < 256; ++k)
        a = fma(h_l[(g << 8) + k], (double)ow1[k * 64 + j], a);
      o1_l[g][j] = fmax(a, 0.0);
      asm volatile("s_waitcnt lgkmcnt(0)" ::: "memory");
      __builtin_amdgcn_wave_barrier();
      // L2: 64 -> 64
      double bacc = (double)ob2[j];
#pragma unroll 4
      for (int k = 0; k < 64; ++k)
        bacc = fma(o1_l[g][k], (double)ow2[k * 64 + j], bacc);
      o2_l[g][j] = fmax(bacc, 0.0);
      asm volatile("s_waitcnt lgkmcnt(0)" ::: "memory");
      __builtin_amdgcn_wave_barrier();
      // L3: 64 -> 6, gia feedback (parity buffer), output stores
      if (j < 6) {
        double d = (double)ob3[j];
#pragma unroll 4
        for (int k = 0; k < 64; ++k) d = fma(o2_l[g][k], (double)ow3[k * 6 + j], d);
        const double gi_new = giab[step & 1][g * 6 + j] + d;
        giab[(step + 1) & 1][g * 6 + j] = gi_new;
        const int s = s0 + g;
        dout[s * 300 + step * 6 + j] = (float)d;              // dws
        dout[76800 + s * 300 + step * 6 + j] = (float)gi_new; // ws
      }
    }
    __syncthreads();                    // pp + gia(parity) ready
  }
#undef MV_BODY
}

extern "C" void kernel_launch(void* const* d_in, const int* in_sizes, int n_in,
                              void* d_out, int out_size, void* d_ws, size_t ws_size,
                              hipStream_t stream) {
  const float* data = (const float*)d_in[0];
  // d_in[1] = horizon (always 50)
  const float* ew1 = (const float*)d_in[2];
  const float* eb1 = (const float*)d_in[3];
  const float* ew2 = (const float*)d_in[4];
  const float* eb2 = (const float*)d_in[5];
  const float* ew3 = (const float*)d_in[6];
  const float* eb3 = (const float*)d_in[7];
  const float* mw1 = (const float*)d_in[8];
  const float* mb1 = (const float*)d_in[9];
  const float* mw2 = (const float*)d_in[10];
  const float* mb2 = (const float*)d_in[11];
  const float* mw3 = (const float*)d_in[12];
  const float* mb3 = (const float*)d_in[13];
  const float* wih = (const float*)d_in[14];
  const float* whh = (const float*)d_in[15];
  const float* bih = (const float*)d_in[16];
  const float* bhh = (const float*)d_in[17];
  const float* ow1 = (const float*)d_in[18];
  const float* ob1 = (const float*)d_in[19];
  const float* ow2 = (const float*)d_in[20];
  const float* ob2 = (const float*)d_in[21];
  const float* ow3 = (const float*)d_in[22];
  const float* ob3 = (const float*)d_in[23];
  float* out = (float*)d_out;

  char* ws = (char*)d_ws;
  float*    wq   = (float*)(ws);                 // 786432 B
  unsigned* henc = (unsigned*)(ws + 786432);     // 524288 B -> end 1310720

  prep_kernel<<<768, 256, 0, stream>>>(whh, wq, henc);
  enc_kernel<<<512, 512, 0, stream>>>(data, ew1, eb1, ew2, eb2, ew3, eb3, henc);
  gru_kernel<<<128, 640, 0, stream>>>((const float*)henc,
                                      mw1, mb1, mw2, mb2, mw3, mb3,
                                      wih, wq, bih, bhh,
                                      ow1, ob1, ow2, ob2, ow3, ob3,
                                      out);
}